// Round 2
// baseline (1181.999 us; speedup 1.0000x reference)
//
#include <hip/hip_runtime.h>
#include <cstdint>

#define B_ 64
#define N_ 512
#define D_ 256
#define L_ 4

typedef __bf16 bf16;
typedef __attribute__((ext_vector_type(8))) __bf16 bf16x8;
typedef __attribute__((ext_vector_type(4))) __bf16 bf16x4;
typedef __attribute__((ext_vector_type(4))) float f32x4;

#define MFMA16(a, b, c) __builtin_amdgcn_mfma_f32_16x16x32_bf16((a), (b), (c), 0, 0, 0)

__device__ __forceinline__ void async_copy16(void* lds, const void* glb) {
  __builtin_amdgcn_global_load_lds(
      (const __attribute__((address_space(1))) void*)glb,
      (__attribute__((address_space(3))) void*)lds, 16, 0, 0);
}

__device__ __forceinline__ float sigmoidf_(float z) {
  return 1.0f / (1.0f + __expf(-z));
}

// ---------------------------------------------------------------------------
// Generic bf16 GEMM:  C[m][n] = sum_k A[m][k] * Bm[n][k]   (i.e. A * Bm^T)
// Tiles: BM=BN=128, BK=32; 4 waves, each a 64x64 quadrant (4x4 MFMA tiles).
// Epilogue: +bias, optional relu, optional +resid(f32); stores to outF (f32),
// outB (bf16), outT (bf16 transposed [b][d][n]).
// grid = (Nout/128, M/128, nbatch)
// ---------------------------------------------------------------------------
__global__ __launch_bounds__(256, 2) void gemm_bt(
    const bf16* __restrict__ A, const bf16* __restrict__ Bm,
    const float* __restrict__ bias, const float* __restrict__ resid,
    float* __restrict__ outF, bf16* __restrict__ outB, bf16* __restrict__ outT,
    int M, int K, int lda, int ldb, int ldc,
    long long sA, long long sB, long long sC, int relu)
{
  __shared__ bf16 As[128 * 32];
  __shared__ bf16 Bs[128 * 32];
  const int tid = threadIdx.x;
  const int w = tid >> 6, lane = tid & 63;
  const int l16 = lane & 15, quad = lane >> 4;
  const int wm = w & 1, wn = w >> 1;
  const int bx = blockIdx.x, by = blockIdx.y, bz = blockIdx.z;
  A  += (size_t)bz * sA;
  Bm += (size_t)bz * sB;
  const size_t cofs = (size_t)bz * sC;

  f32x4 acc[4][4] = {};

  const int arow = lane >> 2;
  const int acg  = (lane & 3) ^ ((lane >> 3) & 3);
  const int sw   = (quad ^ ((l16 >> 1) & 3)) << 3;

  const int nk = K >> 5;
  for (int kc = 0; kc < nk; ++kc) {
    const int k0 = kc << 5;
#pragma unroll
    for (int r = 0; r < 2; ++r) {
      const int c = w + (r << 2);
      const int row = (c << 4) + arow;
      async_copy16(&As[c * 512],
                   A + (size_t)(by * 128 + row) * lda + k0 + (acg << 3));
      async_copy16(&Bs[c * 512],
                   Bm + (size_t)(bx * 128 + row) * ldb + k0 + (acg << 3));
    }
    __syncthreads();
    bf16x8 af[4], bfv[4];
#pragma unroll
    for (int i = 0; i < 4; ++i) {
      af[i]  = *(const bf16x8*)&As[(wm * 64 + i * 16 + l16) * 32 + sw];
      bfv[i] = *(const bf16x8*)&Bs[(wn * 64 + i * 16 + l16) * 32 + sw];
    }
#pragma unroll
    for (int i = 0; i < 4; ++i)
#pragma unroll
      for (int j = 0; j < 4; ++j)
        acc[i][j] = MFMA16(af[i], bfv[j], acc[i][j]);
    __syncthreads();
  }

  const int rbase = by * 128 + wm * 64 + (quad << 2);
  const int cbase = bx * 128 + wn * 64 + l16;
#pragma unroll
  for (int j = 0; j < 4; ++j) {
    const int col = cbase + j * 16;
    const float bv = bias ? bias[col] : 0.0f;
#pragma unroll
    for (int i = 0; i < 4; ++i) {
      const int r0 = rbase + i * 16;
      float v[4];
#pragma unroll
      for (int r = 0; r < 4; ++r) {
        float t = acc[i][j][r] + bv;
        if (relu) t = fmaxf(t, 0.0f);
        if (resid) t += resid[cofs + (size_t)(r0 + r) * ldc + col];
        v[r] = t;
      }
      if (outF) {
#pragma unroll
        for (int r = 0; r < 4; ++r)
          outF[cofs + (size_t)(r0 + r) * ldc + col] = v[r];
      }
      if (outB) {
#pragma unroll
        for (int r = 0; r < 4; ++r)
          outB[cofs + (size_t)(r0 + r) * ldc + col] = (bf16)v[r];
      }
      if (outT) {
        bf16x4 tv;
#pragma unroll
        for (int r = 0; r < 4; ++r) tv[r] = (bf16)v[r];
        *(bf16x4*)&outT[((size_t)(r0 >> 9)) * (D_ * N_) + (size_t)col * N_ +
                        (r0 & (N_ - 1))] = tv;
      }
    }
  }
}

// ---------------------------------------------------------------------------
// Fully fused attention layer, one block per (16-row tile, batch):
//   q   = x_tile @ Wa^T + ba                     (MFMA, B from L2)
//   S   = sigmoid(q @ x_b^T); diag/adj mask      (MFMA, B from L2)
//   rs  = rowsum(S) via in-register shfl_xor within MFMA quad
//   S  /= rs;  store to outA (f32);  S -> LDS bf16 (A-layout transform)
//   x'  = S @ x_b                                (MFMA, B = xT rows from L2)
// grid = (N/16, B), 256 threads = 4 waves.
// ---------------------------------------------------------------------------
__global__ __launch_bounds__(256, 3) void attn_fused(
    const bf16* __restrict__ xb, const bf16* __restrict__ xT,
    const bf16* __restrict__ Wa, const float* __restrict__ ba,
    const float* __restrict__ adj, float* __restrict__ outA,
    bf16* __restrict__ xout)
{
  __shared__ bf16 xs[16 * 264];
  __shared__ bf16 qs[16 * 264];
  __shared__ bf16 Ss[16 * 520];
  __shared__ float psum[4][16];
  const int tid = threadIdx.x, w = tid >> 6, lane = tid & 63;
  const int l16 = lane & 15, quad = lane >> 4;
  const int row0 = blockIdx.x * 16, b = blockIdx.y;

  // ---- load x tile [16][256] into LDS (coalesced 16B x2) ----
#pragma unroll
  for (int e = 0; e < 2; ++e) {
    const int cc = tid + e * 256;
    const int r = cc >> 5, cg = cc & 31;
    bf16x8 v = *(const bf16x8*)(xb + ((size_t)(b * N_ + row0 + r)) * D_ + cg * 8);
    *(bf16x8*)&xs[r * 264 + cg * 8] = v;
  }
  __syncthreads();

  // ---- phase 1: q = x @ Wa^T + ba  -> qs (bf16) ----
  {
    f32x4 aq[4] = {};
    for (int ks = 0; ks < 8; ++ks) {
      const bf16x8 af = *(const bf16x8*)&xs[l16 * 264 + ks * 32 + quad * 8];
      bf16x8 bw[4];
#pragma unroll
      for (int i = 0; i < 4; ++i) {
        const int o = (w * 4 + i) * 16 + l16;
        bw[i] = *(const bf16x8*)(Wa + (size_t)o * D_ + ks * 32 + quad * 8);
      }
#pragma unroll
      for (int i = 0; i < 4; ++i) aq[i] = MFMA16(af, bw[i], aq[i]);
    }
#pragma unroll
    for (int i = 0; i < 4; ++i) {
      const int col = (w * 4 + i) * 16 + l16;
      const float bv = ba[col];
#pragma unroll
      for (int r = 0; r < 4; ++r)
        qs[(quad * 4 + r) * 264 + col] = (bf16)(aq[i][r] + bv);
    }
  }
  __syncthreads();

  // ---- phase 2: S_logits = q @ x^T  (cols j = w*128 .. w*128+127) ----
  f32x4 acc[8] = {};
  for (int ks = 0; ks < 8; ++ks) {
    const bf16x8 af = *(const bf16x8*)&qs[l16 * 264 + ks * 32 + quad * 8];
    bf16x8 bb[8];
#pragma unroll
    for (int t = 0; t < 8; ++t) {
      const int j = (w * 8 + t) * 16 + l16;
      bb[t] = *(const bf16x8*)(xb + ((size_t)(b * N_ + j)) * D_ + ks * 32 + quad * 8);
    }
#pragma unroll
    for (int t = 0; t < 8; ++t) acc[t] = MFMA16(af, bb[t], acc[t]);
  }

  // ---- phase 3: sigmoid + diag + mask, in-register rowsum ----
  float av[8][4];
#pragma unroll
  for (int t = 0; t < 8; ++t) {
    const int gcol = (w * 8 + t) * 16 + l16;
#pragma unroll
    for (int r = 0; r < 4; ++r) {
      const int grow = row0 + quad * 4 + r;
      av[t][r] = adj[((size_t)b * N_ + grow) * N_ + gcol];
    }
  }
  float p[4] = {0.f, 0.f, 0.f, 0.f};
#pragma unroll
  for (int t = 0; t < 8; ++t) {
    const int gcol = (w * 8 + t) * 16 + l16;
#pragma unroll
    for (int r = 0; r < 4; ++r) {
      const int grow = row0 + quad * 4 + r;
      float sg = sigmoidf_(acc[t][r]);
      float a = av[t][r];
      if (grow == gcol) { sg += 1e-5f; a = 1.0f; }
      const float v = sg * a;
      acc[t][r] = v;
      p[r] += v;
    }
  }
#pragma unroll
  for (int r = 0; r < 4; ++r) {
#pragma unroll
    for (int m = 1; m < 16; m <<= 1) p[r] += __shfl_xor(p[r], m, 64);
  }
  if (l16 == 0) {
#pragma unroll
    for (int r = 0; r < 4; ++r) psum[w][quad * 4 + r] = p[r];
  }
  __syncthreads();
  float rinv[4];
#pragma unroll
  for (int r = 0; r < 4; ++r) {
    const int rr = quad * 4 + r;
    rinv[r] = 1.0f / (psum[0][rr] + psum[1][rr] + psum[2][rr] + psum[3][rr]);
  }

  // ---- normalize; store attls (f32); stage S into LDS (bf16, A-layout) ----
  const size_t obase = ((size_t)b * N_ + row0) * N_;
#pragma unroll
  for (int t = 0; t < 8; ++t) {
    const int gcol = (w * 8 + t) * 16 + l16;
#pragma unroll
    for (int r = 0; r < 4; ++r) {
      const int lrow = quad * 4 + r;
      const float v = acc[t][r] * rinv[r];
      outA[obase + (size_t)lrow * N_ + gcol] = v;
      Ss[lrow * 520 + gcol] = (bf16)v;
    }
  }
  __syncthreads();

  // ---- phase 4: x' = S @ x  (out cols d = w*64 .. w*64+63, K = 512) ----
  f32x4 a2[4] = {};
  for (int ks = 0; ks < 16; ++ks) {
    const bf16x8 af = *(const bf16x8*)&Ss[l16 * 520 + ks * 32 + quad * 8];
    bf16x8 bb[4];
#pragma unroll
    for (int i = 0; i < 4; ++i) {
      const int d = (w * 4 + i) * 16 + l16;
      bb[i] = *(const bf16x8*)(xT + ((size_t)(b * D_ + d)) * N_ + ks * 32 + quad * 8);
    }
#pragma unroll
    for (int i = 0; i < 4; ++i) a2[i] = MFMA16(af, bb[i], a2[i]);
  }
#pragma unroll
  for (int i = 0; i < 4; ++i) {
    const int d = (w * 4 + i) * 16 + l16;
#pragma unroll
    for (int r = 0; r < 4; ++r) {
      const int row = row0 + quad * 4 + r;
      xout[((size_t)(b * N_ + row)) * D_ + d] = (bf16)a2[i][r];
    }
  }
}

// ---------------------------------------------------------------------------
// init: x -> out_x (f32 master), x_bf16, xT_bf16 (LDS 32x32 transpose)
// ---------------------------------------------------------------------------
__global__ __launch_bounds__(256) void init_x(
    const float* __restrict__ x, float* __restrict__ outX,
    bf16* __restrict__ xb, bf16* __restrict__ xT)
{
  __shared__ float t[32 * 33];
  const int tid = threadIdx.x;
  const int nt = blockIdx.x, dt = blockIdx.y, b = blockIdx.z;
#pragma unroll
  for (int e = 0; e < 4; ++e) {
    const int idx = tid + e * 256;
    const int r = idx >> 5, c = idx & 31;
    const size_t g = ((size_t)(b * N_ + nt * 32 + r)) * D_ + dt * 32 + c;
    const float v = x[g];
    outX[g] = v;
    xb[g] = (bf16)v;
    t[r * 33 + c] = v;
  }
  __syncthreads();
#pragma unroll
  for (int e = 0; e < 4; ++e) {
    const int idx = tid + e * 256;
    const int r = idx >> 5, c = idx & 31;
    xT[((size_t)(b * D_ + dt * 32 + r)) * N_ + nt * 32 + c] = (bf16)t[c * 33 + r];
  }
}

__global__ __launch_bounds__(256) void cvt_bf16(
    const float* __restrict__ src, bf16* __restrict__ dst, int n4)
{
  const int i = blockIdx.x * 256 + threadIdx.x;
  if (i < n4) {
    const float4 v = ((const float4*)src)[i];
    bf16x4 o;
    o[0] = (bf16)v.x; o[1] = (bf16)v.y; o[2] = (bf16)v.z; o[3] = (bf16)v.w;
    ((bf16x4*)dst)[i] = o;
  }
}

extern "C" void kernel_launch(void* const* d_in, const int* in_sizes, int n_in,
                              void* d_out, int out_size, void* d_ws, size_t ws_size,
                              hipStream_t stream)
{
  const float* x_in  = (const float*)d_in[0];
  const float* adj   = (const float*)d_in[1];
  const float* wattn = (const float*)d_in[2];
  const float* battn = (const float*)d_in[3];
  const float* w0    = (const float*)d_in[4];
  const float* b0    = (const float*)d_in[5];
  const float* w1    = (const float*)d_in[6];
  const float* b1    = (const float*)d_in[7];
  const float* wf    = (const float*)d_in[8];
  const float* bfin  = (const float*)d_in[9];

  float* out_x    = (float*)d_out;                     // [B,N,D] f32 master
  float* out_attn = out_x + (size_t)B_ * N_ * D_;      // [L,B,N,N]

  bf16* wb = (bf16*)d_ws;                              // 13 * D*D weights
  bf16* xb = wb + 13 * (D_ * D_);                      // [B,N,D] bf16
  bf16* xT = xb + (size_t)B_ * N_ * D_;                // [B,D,N] bf16
  bf16* qb = xT + (size_t)B_ * N_ * D_;                // x' (attn output)
  bf16* hb = qb + (size_t)B_ * N_ * D_;                // lin0 output

  const int DD2 = D_ * D_;
  const int Mfull = B_ * N_;  // 32768

  cvt_bf16<<<dim3((L_ * DD2 / 4 + 255) / 256), 256, 0, stream>>>(wattn, wb, L_ * DD2 / 4);
  cvt_bf16<<<dim3((L_ * DD2 / 4 + 255) / 256), 256, 0, stream>>>(w0, wb + 4 * DD2, L_ * DD2 / 4);
  cvt_bf16<<<dim3((L_ * DD2 / 4 + 255) / 256), 256, 0, stream>>>(w1, wb + 8 * DD2, L_ * DD2 / 4);
  cvt_bf16<<<dim3((DD2 / 4 + 255) / 256), 256, 0, stream>>>(wf, wb + 12 * DD2, DD2 / 4);

  init_x<<<dim3(N_ / 32, D_ / 32, B_), 256, 0, stream>>>(x_in, out_x, xb, xT);

  for (int l = 0; l < L_; ++l) {
    // fused: q-proj + attention + normalize + attls store + x' = S@x
    attn_fused<<<dim3(N_ / 16, B_), 256, 0, stream>>>(
        xb, xT, wb + l * DD2, battn + l * D_, adj,
        out_attn + (size_t)l * B_ * N_ * N_, qb);
    // h = relu(x' @ W0^T + b0)
    gemm_bt<<<dim3(2, Mfull / 128, 1), 256, 0, stream>>>(
        qb, wb + (4 + l) * DD2, b0 + l * D_, nullptr,
        nullptr, hb, nullptr,
        Mfull, D_, D_, D_, D_, 0, 0, 0, 1);
    // x = relu(h @ W1^T + b1) + x0 -> out_x (f32), xb, xT
    gemm_bt<<<dim3(2, Mfull / 128, 1), 256, 0, stream>>>(
        hb, wb + (8 + l) * DD2, b1 + l * D_, out_x,
        out_x, xb, xT,
        Mfull, D_, D_, D_, D_, 0, 0, 0, 1);
  }
  gemm_bt<<<dim3(2, Mfull / 128, 1), 256, 0, stream>>>(
      xb, wb + 12 * DD2, bfin, nullptr,
      out_x, nullptr, nullptr,
      Mfull, D_, D_, D_, D_, 0, 0, 0, 0);
}